// Round 7
// baseline (60.390 us; speedup 1.0000x reference)
//
#include <hip/hip_runtime.h>

// CRPS loss, mean reduction.
// forecasts: (N=20, M) f32 where M = B*C*D*H*W; target: (M,) f32; out: scalar f32.
// crps(m) = (1/N) sum_i |x_i - y| - (1/N^2) sum_{i<j} |x_i - x_j|
// out = mean_m crps(m)
//
// R7 = R6 intent with compile fix: __builtin_nontemporal_load needs a clang
// vector type, not HIP_vector_type<float,4>. Use ext_vector_type(4) float.
// nt dwordx4 loads: read-once 264MB stream (103% of L3) must not allocate in
// cache (R5: +23% from nt alone); x4 width cuts VMEM requests 4x.
// NO forced launch bounds (R2 lesson: forcing 8 waves with ~85 live VGPRs
// spills to scratch). ~110 VGPR -> 4 waves/SIMD naturally; in-flight bytes
// 4w x 20 x 1KiB = 80KB/CU >> latency product -> occupancy sufficient.

constexpr int NS = 20;          // sample count (compile-time for full unroll)
constexpr int BLOCK = 256;

typedef float floatv4 __attribute__((ext_vector_type(4)));

__global__ __launch_bounds__(BLOCK) void crps_partial_kernel(
    const float* __restrict__ forecasts,
    const float* __restrict__ target,
    float* __restrict__ partial,   // one float per block
    int M4)                        // positions in float4 units
{
    const int idx = blockIdx.x * BLOCK + threadIdx.x;
    float local = 0.0f;

    if (idx < M4) {
        const floatv4* __restrict__ f4 = reinterpret_cast<const floatv4*>(forecasts);
        const floatv4* __restrict__ t4 = reinterpret_cast<const floatv4*>(target);

        // 20 nontemporal dwordx4 loads (read-once stream, no L2/L3 alloc).
        float x0[NS], x1[NS], x2[NS], x3[NS];
        #pragma unroll
        for (int i = 0; i < NS; ++i) {
            floatv4 v = __builtin_nontemporal_load(&f4[(size_t)i * (size_t)M4 + idx]);
            x0[i] = v.x; x1[i] = v.y; x2[i] = v.z; x3[i] = v.w;
        }
        floatv4 tv = __builtin_nontemporal_load(&t4[idx]);

        float first = 0.0f;
        #pragma unroll
        for (int i = 0; i < NS; ++i)
            first += fabsf(x0[i] - tv.x) + fabsf(x1[i] - tv.y)
                   + fabsf(x2[i] - tv.z) + fabsf(x3[i] - tv.w);

        float pair = 0.0f;
        #pragma unroll
        for (int i = 0; i < NS; ++i)
            #pragma unroll
            for (int j = i + 1; j < NS; ++j)
                pair += fabsf(x0[i] - x0[j]) + fabsf(x1[i] - x1[j])
                      + fabsf(x2[i] - x2[j]) + fabsf(x3[i] - x3[j]);

        local = first * (1.0f / NS) - pair * (1.0f / (NS * NS));
    }

    // Wave (64-lane) shuffle reduce, then cross-wave via LDS.
    #pragma unroll
    for (int off = 32; off > 0; off >>= 1)
        local += __shfl_down(local, off, 64);

    __shared__ float wsum[BLOCK / 64];
    const int lane = threadIdx.x & 63;
    const int wid  = threadIdx.x >> 6;
    if (lane == 0) wsum[wid] = local;
    __syncthreads();
    if (threadIdx.x == 0) {
        float s = 0.0f;
        #pragma unroll
        for (int w = 0; w < BLOCK / 64; ++w) s += wsum[w];
        partial[blockIdx.x] = s;
    }
}

__global__ __launch_bounds__(BLOCK) void crps_final_kernel(
    const float* __restrict__ partial,   // nblocks floats
    int nblocks,
    float* __restrict__ out,
    float invM)
{
    // Fixed per-thread order + fixed tree -> deterministic.
    float s = 0.0f;
    for (int i = threadIdx.x; i < nblocks; i += BLOCK)
        s += partial[i];

    #pragma unroll
    for (int off = 32; off > 0; off >>= 1)
        s += __shfl_down(s, off, 64);

    __shared__ float wsum[BLOCK / 64];
    const int lane = threadIdx.x & 63;
    const int wid  = threadIdx.x >> 6;
    if (lane == 0) wsum[wid] = s;
    __syncthreads();
    if (threadIdx.x == 0) {
        float tot = 0.0f;
        #pragma unroll
        for (int w = 0; w < BLOCK / 64; ++w) tot += wsum[w];
        out[0] = tot * invM;
    }
}

extern "C" void kernel_launch(void* const* d_in, const int* in_sizes, int n_in,
                              void* d_out, int out_size, void* d_ws, size_t ws_size,
                              hipStream_t stream) {
    const float* forecasts = (const float*)d_in[0];
    const float* target    = (const float*)d_in[1];
    float* out = (float*)d_out;
    float* partial = (float*)d_ws;

    const int M  = in_sizes[1];          // B*C*D*H*W = 3,145,728
    const int M4 = M >> 2;               // 786,432 float4 positions
    const int nblocks = (M4 + BLOCK - 1) / BLOCK;   // 3072

    crps_partial_kernel<<<nblocks, BLOCK, 0, stream>>>(forecasts, target, partial, M4);
    crps_final_kernel<<<1, BLOCK, 0, stream>>>(partial, nblocks, out, 1.0f / (float)M);
}

// Round 8
// 58.342 us; speedup vs baseline: 1.0351x; 1.0351x over previous
//
#include <hip/hip_runtime.h>

// CRPS loss, mean reduction.
// forecasts: (N=20, M) f32 where M = B*C*D*H*W; target: (M,) f32; out: scalar f32.
// crps(m) = (1/N) sum_i |x_i - y| - (1/N^2) sum_{i<j} |x_i - x_j|
// out = mean_m crps(m)
//
// R8: R5 structure (nt + grid-stride 2048 blocks) with float2 loads and
// launch_bounds(256,6). Ladder: dword+nt+8w = 47.7us; float4+nt+low-occ =
// 60.4us (VGPR ballooned, occupancy loss exposed full nt/HBM latency).
// float2 halves request count vs dword; ~60 live VGPRs fit the 6-wave cap
// (~80) with margin -> no spill (R2: bound-8 made the allocator clamp to
// 32 VGPR and spill 1GB; never force past the live set).

constexpr int NS = 20;          // sample count (compile-time for full unroll)
constexpr int BLOCK = 256;
constexpr int PBLOCKS = 2048;   // 8 blocks/CU on 256 CUs

typedef float floatv2 __attribute__((ext_vector_type(2)));

__global__ __launch_bounds__(BLOCK, 6) void crps_partial_kernel(
    const float* __restrict__ forecasts,
    const float* __restrict__ target,
    float* __restrict__ partial,   // one float per block
    int M2)                        // positions in float2 units
{
    float local = 0.0f;
    const int stride = PBLOCKS * BLOCK;   // 524288 float2 positions per sweep

    const floatv2* __restrict__ f2 = reinterpret_cast<const floatv2*>(forecasts);
    const floatv2* __restrict__ t2 = reinterpret_cast<const floatv2*>(target);

    #pragma unroll 1                      // keep live range per-iteration
    for (int idx = blockIdx.x * BLOCK + threadIdx.x; idx < M2; idx += stride) {
        // 20 nontemporal dwordx2 loads (read-once stream, no L2/L3 alloc).
        float x0[NS], x1[NS];
        #pragma unroll
        for (int i = 0; i < NS; ++i) {
            floatv2 v = __builtin_nontemporal_load(&f2[(size_t)i * (size_t)M2 + idx]);
            x0[i] = v.x; x1[i] = v.y;
        }
        floatv2 tv = __builtin_nontemporal_load(&t2[idx]);

        float first = 0.0f;
        #pragma unroll
        for (int i = 0; i < NS; ++i)
            first += fabsf(x0[i] - tv.x) + fabsf(x1[i] - tv.y);

        float pair = 0.0f;
        #pragma unroll
        for (int i = 0; i < NS; ++i)
            #pragma unroll
            for (int j = i + 1; j < NS; ++j)
                pair += fabsf(x0[i] - x0[j]) + fabsf(x1[i] - x1[j]);

        local += first * (1.0f / NS) - pair * (1.0f / (NS * NS));
    }

    // Wave (64-lane) shuffle reduce, then cross-wave via LDS.
    #pragma unroll
    for (int off = 32; off > 0; off >>= 1)
        local += __shfl_down(local, off, 64);

    __shared__ float wsum[BLOCK / 64];
    const int lane = threadIdx.x & 63;
    const int wid  = threadIdx.x >> 6;
    if (lane == 0) wsum[wid] = local;
    __syncthreads();
    if (threadIdx.x == 0) {
        float s = 0.0f;
        #pragma unroll
        for (int w = 0; w < BLOCK / 64; ++w) s += wsum[w];
        partial[blockIdx.x] = s;
    }
}

__global__ __launch_bounds__(BLOCK) void crps_final_kernel(
    const float* __restrict__ partial,   // PBLOCKS floats
    float* __restrict__ out,
    float invM)
{
    // 8 coalesced loads per thread, fixed order -> deterministic.
    float s = 0.0f;
    #pragma unroll
    for (int k = 0; k < PBLOCKS / BLOCK; ++k)
        s += partial[k * BLOCK + threadIdx.x];

    #pragma unroll
    for (int off = 32; off > 0; off >>= 1)
        s += __shfl_down(s, off, 64);

    __shared__ float wsum[BLOCK / 64];
    const int lane = threadIdx.x & 63;
    const int wid  = threadIdx.x >> 6;
    if (lane == 0) wsum[wid] = s;
    __syncthreads();
    if (threadIdx.x == 0) {
        float tot = 0.0f;
        #pragma unroll
        for (int w = 0; w < BLOCK / 64; ++w) tot += wsum[w];
        out[0] = tot * invM;
    }
}

extern "C" void kernel_launch(void* const* d_in, const int* in_sizes, int n_in,
                              void* d_out, int out_size, void* d_ws, size_t ws_size,
                              hipStream_t stream) {
    const float* forecasts = (const float*)d_in[0];
    const float* target    = (const float*)d_in[1];
    float* out = (float*)d_out;
    float* partial = (float*)d_ws;

    const int M  = in_sizes[1];          // B*C*D*H*W = 3,145,728
    const int M2 = M >> 1;               // 1,572,864 float2 positions

    crps_partial_kernel<<<PBLOCKS, BLOCK, 0, stream>>>(forecasts, target, partial, M2);
    crps_final_kernel<<<1, BLOCK, 0, stream>>>(partial, out, 1.0f / (float)M);
}

// Round 9
// 49.486 us; speedup vs baseline: 1.2204x; 1.1790x over previous
//
#include <hip/hip_runtime.h>

// CRPS loss, mean reduction.
// forecasts: (N=20, M) f32 where M = B*C*D*H*W; target: (M,) f32; out: scalar f32.
// crps(m) = (1/N) sum_i |x_i - y| - (1/N^2) sum_{i<j} |x_i - x_j|
// out = mean_m crps(m)
//
// R9 = revert to R5, the measured optimum (47.7us).
// Width/occupancy ladder in the nt regime (complete A/B):
//   dword + 8 waves/SIMD  = 47.7us   <- this kernel
//   float2 + 6 waves/SIMD = 58.3us
//   float4 + ~3 waves/SIMD= 60.4us
// nt loads (no L2/L3 allocation; working set = 264MB = 103% of L3, read-once)
// bought 61.8 -> 47.7. With cache bypassed, loads see near-full HBM latency,
// so wave count is the only latency cover: occupancy > width, hence scalar
// dword loads (x[20] = 20 VGPRs, total 40 -> true 8 waves/SIMD, no spill).
// Partial kernel: 264.3MB / ~43us = 6.15 TB/s = ~98% of the 6.29 TB/s
// measured read ceiling. Residual ~4us = final-reduce + launch gap.

constexpr int NS = 20;          // sample count (compile-time for full unroll)
constexpr int BLOCK = 256;
constexpr int PBLOCKS = 2048;   // 8 blocks/CU on 256 CUs

__global__ __launch_bounds__(BLOCK, 8) void crps_partial_kernel(
    const float* __restrict__ forecasts,
    const float* __restrict__ target,
    float* __restrict__ partial,   // one float per block
    int M)                         // positions
{
    float local = 0.0f;
    const int stride = PBLOCKS * BLOCK;   // 524288 positions per sweep

    #pragma unroll 1                      // keep x[20] live-range per-iteration
    for (int idx = blockIdx.x * BLOCK + threadIdx.x; idx < M; idx += stride) {
        // 20 strided sample loads, one dword per lane, streaming (nt):
        // read-once data, do not allocate in L2/L3.
        float x[NS];
        #pragma unroll
        for (int i = 0; i < NS; ++i)
            x[i] = __builtin_nontemporal_load(&forecasts[(size_t)i * (size_t)M + idx]);
        const float tv = __builtin_nontemporal_load(&target[idx]);

        float first = 0.0f;
        #pragma unroll
        for (int i = 0; i < NS; ++i)
            first += fabsf(x[i] - tv);

        float pair = 0.0f;
        #pragma unroll
        for (int i = 0; i < NS; ++i)
            #pragma unroll
            for (int j = i + 1; j < NS; ++j)
                pair += fabsf(x[i] - x[j]);

        local += first * (1.0f / NS) - pair * (1.0f / (NS * NS));
    }

    // Wave (64-lane) shuffle reduce, then cross-wave via LDS.
    #pragma unroll
    for (int off = 32; off > 0; off >>= 1)
        local += __shfl_down(local, off, 64);

    __shared__ float wsum[BLOCK / 64];
    const int lane = threadIdx.x & 63;
    const int wid  = threadIdx.x >> 6;
    if (lane == 0) wsum[wid] = local;
    __syncthreads();
    if (threadIdx.x == 0) {
        float s = 0.0f;
        #pragma unroll
        for (int w = 0; w < BLOCK / 64; ++w) s += wsum[w];
        partial[blockIdx.x] = s;
    }
}

__global__ __launch_bounds__(BLOCK) void crps_final_kernel(
    const float* __restrict__ partial,   // PBLOCKS floats
    float* __restrict__ out,
    float invM)
{
    // 8 coalesced loads per thread, fixed order -> deterministic.
    float s = 0.0f;
    #pragma unroll
    for (int k = 0; k < PBLOCKS / BLOCK; ++k)
        s += partial[k * BLOCK + threadIdx.x];

    #pragma unroll
    for (int off = 32; off > 0; off >>= 1)
        s += __shfl_down(s, off, 64);

    __shared__ float wsum[BLOCK / 64];
    const int lane = threadIdx.x & 63;
    const int wid  = threadIdx.x >> 6;
    if (lane == 0) wsum[wid] = s;
    __syncthreads();
    if (threadIdx.x == 0) {
        float tot = 0.0f;
        #pragma unroll
        for (int w = 0; w < BLOCK / 64; ++w) tot += wsum[w];
        out[0] = tot * invM;
    }
}

extern "C" void kernel_launch(void* const* d_in, const int* in_sizes, int n_in,
                              void* d_out, int out_size, void* d_ws, size_t ws_size,
                              hipStream_t stream) {
    const float* forecasts = (const float*)d_in[0];
    const float* target    = (const float*)d_in[1];
    float* out = (float*)d_out;
    float* partial = (float*)d_ws;

    const int M = in_sizes[1];           // B*C*D*H*W = 3,145,728

    crps_partial_kernel<<<PBLOCKS, BLOCK, 0, stream>>>(forecasts, target, partial, M);
    crps_final_kernel<<<1, BLOCK, 0, stream>>>(partial, out, 1.0f / (float)M);
}